// Round 2
// baseline (2739.930 us; speedup 1.0000x reference)
//
#include <hip/hip_runtime.h>
#include <stdint.h>

#define NN 100000
#define NT 500000
#define RP 16
#define RR 16
#define EMB 16
#define NUMCLS 40
#define NRP (NN*RP)   // 1,600,000

// ---------------- kernel: lat1/lat2 softmax + colsum/rowsum scatter ----------------
__global__ __launch_bounds__(256) void k_lat(
    const float* __restrict__ nhots,
    const float* __restrict__ Wl1, const float* __restrict__ bl1,
    const float* __restrict__ Wl2, const float* __restrict__ bl2,
    const int* __restrict__ srow, const int* __restrict__ ocol,
    float* __restrict__ lat1, float* __restrict__ lat2,
    float* __restrict__ colsum, float* __restrict__ rowsum)
{
    __shared__ float sW1[RP*RR], sW2[RP*RR], sb1[RP], sb2[RP];
    int tid = threadIdx.x;
    if (tid < RP*RR){ sW1[tid] = Wl1[tid]; sW2[tid] = Wl2[tid]; }
    if (tid < RP){ sb1[tid] = bl1[tid]; sb2[tid] = bl2[tid]; }
    __syncthreads();

    int t = blockIdx.x * 256 + tid;
    float p01 = 0.f, p02 = 0.f;
    if (t < NT){
        float nh[RR];
        const float4* npx = (const float4*)(nhots + (size_t)t * RR);
        #pragma unroll
        for (int q = 0; q < 4; q++){
            float4 v = npx[q];
            nh[4*q] = v.x; nh[4*q+1] = v.y; nh[4*q+2] = v.z; nh[4*q+3] = v.w;
        }
        float l1[RP], l2[RP];
        #pragma unroll
        for (int r = 0; r < RP; r++){
            float a = sb1[r], b = sb2[r];
            #pragma unroll
            for (int i = 0; i < RR; i++){ a += nh[i] * sW1[r*RR+i]; b += nh[i] * sW2[r*RR+i]; }
            l1[r] = a; l2[r] = b;
        }
        float m1 = l1[0], m2 = l2[0];
        #pragma unroll
        for (int r = 1; r < RP; r++){ m1 = fmaxf(m1, l1[r]); m2 = fmaxf(m2, l2[r]); }
        float s1 = 0.f, s2 = 0.f;
        #pragma unroll
        for (int r = 0; r < RP; r++){
            l1[r] = expf(l1[r] - m1); s1 += l1[r];
            l2[r] = expf(l2[r] - m2); s2 += l2[r];
        }
        float i1 = 1.f / s1, i2 = 1.f / s2;
        #pragma unroll
        for (int r = 0; r < RP; r++){ l1[r] *= i1; l2[r] *= i2; }

        float4* o1 = (float4*)(lat1 + (size_t)t * RP);
        float4* o2 = (float4*)(lat2 + (size_t)t * RP);
        #pragma unroll
        for (int q = 0; q < 4; q++){
            o1[q] = make_float4(l1[4*q], l1[4*q+1], l1[4*q+2], l1[4*q+3]);
            o2[q] = make_float4(l2[4*q], l2[4*q+1], l2[4*q+2], l2[4*q+3]);
        }
        int s = srow[t], o = ocol[t];
        #pragma unroll
        for (int r = 1; r < RP; r++){
            unsafeAtomicAdd(&colsum[(size_t)o * r], l1[r]);
            unsafeAtomicAdd(&rowsum[(size_t)s * r], l2[r]);
        }
        p01 = l1[0]; p02 = l2[0];
    }
    // block-reduce the r=0 contributions (all edges hit segment 0)
    #pragma unroll
    for (int off = 32; off > 0; off >>= 1){
        p01 += __shfl_down(p01, off);
        p02 += __shfl_down(p02, off);
    }
    __shared__ float rbuf[8];
    int wave = tid >> 6, lane = tid & 63;
    if (lane == 0){ rbuf[wave] = p01; rbuf[4 + wave] = p02; }
    __syncthreads();
    if (tid == 0){
        float a = rbuf[0] + rbuf[1] + rbuf[2] + rbuf[3];
        float b = rbuf[4] + rbuf[5] + rbuf[6] + rbuf[7];
        unsafeAtomicAdd(&colsum[0], a);
        unsafeAtomicAdd(&rowsum[0], b);
    }
}

// ---------------- kernel: layer-1 aggregation (4 lanes per edge) ----------------
__global__ __launch_bounds__(256) void k_layer1(
    const int* __restrict__ srow, const int* __restrict__ ocol,
    const float* __restrict__ lat1, const float* __restrict__ colsum,
    const float* __restrict__ w1,   // weights1 fp32, (nrp,16) flat
    float* __restrict__ h)
{
    long gid = (long)blockIdx.x * 256 + threadIdx.x;
    int t = (int)(gid >> 2);
    if (t >= NT) return;
    int j = (int)(gid & 3);
    int s = srow[t], o = ocol[t];
    const float4* lp = (const float4*)(lat1 + (size_t)t * RP);
    float lv[RP];
    #pragma unroll
    for (int q = 0; q < 4; q++){
        float4 v = lp[q];
        lv[4*q] = v.x; lv[4*q+1] = v.y; lv[4*q+2] = v.z; lv[4*q+3] = v.w;
    }
    float4 acc = make_float4(0.f, 0.f, 0.f, 0.f);
    #pragma unroll
    for (int r = 0; r < RP; r++){
        size_t c = (size_t)o * r;
        float v = lv[r] / colsum[c];
        float4 w = *(const float4*)(w1 + c * 16 + j * 4);
        acc.x += v * w.x;
        acc.y += v * w.y;
        acc.z += v * w.z;
        acc.w += v * w.w;
    }
    float* hp = h + (size_t)s * 16 + j * 4;
    unsafeAtomicAdd(hp + 0, acc.x);
    unsafeAtomicAdd(hp + 1, acc.y);
    unsafeAtomicAdd(hp + 2, acc.z);
    unsafeAtomicAdd(hp + 3, acc.w);
}

// ---------------- kernel: h = relu(h + bias1) ----------------
__global__ __launch_bounds__(256) void k_relu(float* __restrict__ h,
                                              const float* __restrict__ bias1)
{
    int idx = blockIdx.x * 256 + threadIdx.x;   // over N*4 float4 groups
    if (idx >= NN * 4) return;
    int eb = (idx & 3) * 4;
    float4 v = ((float4*)h)[idx];
    v.x = fmaxf(v.x + bias1[eb+0], 0.f);
    v.y = fmaxf(v.y + bias1[eb+1], 0.f);
    v.z = fmaxf(v.z + bias1[eb+2], 0.f);
    v.w = fmaxf(v.w + bias1[eb+3], 0.f);
    ((float4*)h)[idx] = v;
}

// ---------------- kernel: layer-2 scatter into h2 (4 lanes per edge) ----------------
__global__ __launch_bounds__(256) void k_layer2(
    const int* __restrict__ srow, const int* __restrict__ ocol,
    const float* __restrict__ lat2, const float* __restrict__ rowsum,
    const float* __restrict__ h, float* __restrict__ h2)
{
    int tid = threadIdx.x;
    long gid = (long)blockIdx.x * 256 + tid;
    int t = (int)(gid >> 2);
    int j = tid & 3;
    float4 p0 = make_float4(0.f, 0.f, 0.f, 0.f);
    if (t < NT){
        int s = srow[t], o = ocol[t];
        float4 hv = ((const float4*)h)[(size_t)o * 4 + j];
        const float* l2row = lat2 + (size_t)t * RP;
        float v0 = l2row[0] / rowsum[0];
        p0.x = v0 * hv.x; p0.y = v0 * hv.y; p0.z = v0 * hv.z; p0.w = v0 * hv.w;
        #pragma unroll
        for (int r = 1; r < RP; r++){
            size_t c = (size_t)s * r;
            float v = l2row[r] / rowsum[c];
            float* dst = h2 + c * 16 + j * 4;
            unsafeAtomicAdd(dst + 0, v * hv.x);
            unsafeAtomicAdd(dst + 1, v * hv.y);
            unsafeAtomicAdd(dst + 2, v * hv.z);
            unsafeAtomicAdd(dst + 3, v * hv.w);
        }
    }
    // block-reduce r=0 contributions (all edges scatter into h2 flat row 0)
    __shared__ float red[256 * 4];
    red[tid*4+0] = p0.x; red[tid*4+1] = p0.y; red[tid*4+2] = p0.z; red[tid*4+3] = p0.w;
    __syncthreads();
    if (tid < 16){
        int jj = tid >> 2, kk = tid & 3;
        float sum = 0.f;
        for (int e = 0; e < 64; e++) sum += red[(e*4 + jj)*4 + kk];
        unsafeAtomicAdd(&h2[tid], sum);
    }
}

// ---------------- kernel: out[n,c] = bias2[c] + sum_{r,h} w2[r,h,c]*h2[r*N+n,h] ----------------
__global__ __launch_bounds__(256) void k_out(
    const float* __restrict__ h2, const float* __restrict__ w2,
    const float* __restrict__ b2, float* __restrict__ out)
{
    int n = blockIdx.x * 256 + threadIdx.x;
    if (n >= NN) return;
    float acc[NUMCLS];
    #pragma unroll
    for (int c = 0; c < NUMCLS; c++) acc[c] = b2[c];
    for (int r = 0; r < RP; r++){
        const float4* hp = (const float4*)(h2 + ((size_t)r * NN + n) * 16);
        float hv[EMB];
        #pragma unroll
        for (int q = 0; q < 4; q++){
            float4 v = hp[q];
            hv[4*q] = v.x; hv[4*q+1] = v.y; hv[4*q+2] = v.z; hv[4*q+3] = v.w;
        }
        #pragma unroll
        for (int e = 0; e < EMB; e++){
            float x = hv[e];
            const float* wrow = w2 + ((size_t)r * EMB + e) * NUMCLS;  // wave-uniform -> s_load
            #pragma unroll
            for (int c = 0; c < NUMCLS; c++) acc[c] += x * wrow[c];
        }
    }
    float4* op = (float4*)(out + (size_t)n * NUMCLS);
    #pragma unroll
    for (int q = 0; q < NUMCLS/4; q++){
        op[q] = make_float4(acc[4*q], acc[4*q+1], acc[4*q+2], acc[4*q+3]);
    }
}

extern "C" void kernel_launch(void* const* d_in, const int* in_sizes, int n_in,
                              void* d_out, int out_size, void* d_ws, size_t ws_size,
                              hipStream_t stream)
{
    const float* nhots = (const float*)d_in[0];
    const float* Wl1   = (const float*)d_in[1];
    const float* bl1   = (const float*)d_in[2];
    const float* Wl2   = (const float*)d_in[3];
    const float* bl2   = (const float*)d_in[4];
    const float* w1    = (const float*)d_in[5];
    const float* w2    = (const float*)d_in[6];
    const float* b1    = (const float*)d_in[7];
    const float* b2    = (const float*)d_in[8];
    const int* hrow = (const int*)d_in[9];    // hrow[t] = s[t] for t < NT
    const int* vcol = (const int*)d_in[12];   // vcol[t] = o[t] for t < NT

    float* ws = (float*)d_ws;
    float* lat1   = ws;                              // NT*16 = 8M floats
    float* lat2   = lat1 + (size_t)NT * RP;          // 8M
    float* colsum = lat2 + (size_t)NT * RP;          // 1.6M
    float* rowsum = colsum + (size_t)NRP;            // 1.6M
    float* h      = rowsum + (size_t)NRP;            // N*16 = 1.6M
    float* h2     = h + (size_t)NN * EMB;            // nrp*16 = 25.6M

    hipMemsetAsync(colsum, 0, (size_t)NRP * 4, stream);
    hipMemsetAsync(rowsum, 0, (size_t)NRP * 4, stream);
    hipMemsetAsync(h,      0, (size_t)NN * EMB * 4, stream);
    hipMemsetAsync(h2,     0, (size_t)NRP * EMB * 4, stream);

    k_lat<<<(NT + 255)/256, 256, 0, stream>>>(nhots, Wl1, bl1, Wl2, bl2,
                                              hrow, vcol, lat1, lat2, colsum, rowsum);
    k_layer1<<<((size_t)NT*4 + 255)/256, 256, 0, stream>>>(hrow, vcol, lat1, colsum, w1, h);
    k_relu<<<(NN*4 + 255)/256, 256, 0, stream>>>(h, b1);
    k_layer2<<<((size_t)NT*4 + 255)/256, 256, 0, stream>>>(hrow, vcol, lat2, rowsum, h, h2);
    k_out<<<(NN + 255)/256, 256, 0, stream>>>(h2, w2, b2, (float*)d_out);
}

// Round 3
// 911.862 us; speedup vs baseline: 3.0048x; 3.0048x over previous
//
#include <hip/hip_runtime.h>
#include <stdint.h>

#define NN 100000
#define NT 500000
#define RP 16
#define RR 16
#define EMB 16
#define NUMCLS 40
#define NRP (NN*RP)          // 1,600,000
#define MM (2*NN)            // concatenated histogram length (by-s | by-o)
#define SCAN_BLOCKS ((MM + 255)/256)   // 782

// ============ CSR build ============
__global__ __launch_bounds__(256) void k_count(const int* __restrict__ s,
                                               const int* __restrict__ o,
                                               int* __restrict__ cnt){
    int t = blockIdx.x*256 + threadIdx.x;
    if (t >= NT) return;
    atomicAdd(&cnt[s[t]], 1);
    atomicAdd(&cnt[NN + o[t]], 1);
}

__global__ __launch_bounds__(256) void k_scan_blk(const int* __restrict__ cnt,
                                                  int* __restrict__ offs,
                                                  int* __restrict__ bsum){
    __shared__ int sm[256];
    int tid = threadIdx.x;
    int i = blockIdx.x*256 + tid;
    int v = (i < MM) ? cnt[i] : 0;
    sm[tid] = v; __syncthreads();
    for (int off = 1; off < 256; off <<= 1){
        int x = (tid >= off) ? sm[tid-off] : 0;
        __syncthreads();
        sm[tid] += x; __syncthreads();
    }
    if (i < MM) offs[i] = sm[tid] - v;       // exclusive within block
    if (tid == 255) bsum[blockIdx.x] = sm[255];
}

__global__ __launch_bounds__(1024) void k_scan_top(const int* __restrict__ bsum,
                                                   int* __restrict__ btot){
    __shared__ int sm[1024];
    int tid = threadIdx.x;
    int v = (tid < SCAN_BLOCKS) ? bsum[tid] : 0;
    sm[tid] = v; __syncthreads();
    for (int off = 1; off < 1024; off <<= 1){
        int x = (tid >= off) ? sm[tid-off] : 0;
        __syncthreads();
        sm[tid] += x; __syncthreads();
    }
    if (tid < SCAN_BLOCKS) btot[tid] = sm[tid] - v;   // exclusive
}

__global__ __launch_bounds__(256) void k_scan_add(int* __restrict__ offs,
                                                  const int* __restrict__ btot,
                                                  int* __restrict__ cur){
    int i = blockIdx.x*256 + threadIdx.x;
    if (i < MM){
        int v = offs[i] + btot[blockIdx.x];
        offs[i] = v;
        cur[i] = v;
    }
    if (i == 0) offs[MM] = 2*NT;
}

__global__ __launch_bounds__(256) void k_fill(const int* __restrict__ s,
                                              const int* __restrict__ o,
                                              int* __restrict__ cur,
                                              int* __restrict__ eb){
    int t = blockIdx.x*256 + threadIdx.x;
    if (t >= NT) return;
    int p = atomicAdd(&cur[s[t]], 1);      eb[p] = t;   // by-s list in [0, NT)
    int q = atomicAdd(&cur[NN + o[t]], 1); eb[q] = t;   // by-o list in [NT, 2NT)
}

// ============ lat1/lat2 softmax (pure streaming, no atomics) ============
__global__ __launch_bounds__(256) void k_lat(
    const float* __restrict__ nhots,
    const float* __restrict__ Wl1, const float* __restrict__ bl1,
    const float* __restrict__ Wl2, const float* __restrict__ bl2,
    float* __restrict__ lat1, float* __restrict__ lat2)
{
    __shared__ float sW1[RP*RR], sW2[RP*RR], sb1[RP], sb2[RP];
    int tid = threadIdx.x;
    if (tid < RP*RR){ sW1[tid] = Wl1[tid]; sW2[tid] = Wl2[tid]; }
    if (tid < RP){ sb1[tid] = bl1[tid]; sb2[tid] = bl2[tid]; }
    __syncthreads();

    int t = blockIdx.x*256 + tid;
    if (t >= NT) return;
    float nh[RR];
    const float4* npx = (const float4*)(nhots + (size_t)t * RR);
    #pragma unroll
    for (int q = 0; q < 4; q++){
        float4 v = npx[q];
        nh[4*q] = v.x; nh[4*q+1] = v.y; nh[4*q+2] = v.z; nh[4*q+3] = v.w;
    }
    float l1[RP], l2[RP];
    #pragma unroll
    for (int r = 0; r < RP; r++){
        float a = sb1[r], b = sb2[r];
        #pragma unroll
        for (int i = 0; i < RR; i++){ a += nh[i]*sW1[r*RR+i]; b += nh[i]*sW2[r*RR+i]; }
        l1[r] = a; l2[r] = b;
    }
    float m1 = l1[0], m2 = l2[0];
    #pragma unroll
    for (int r = 1; r < RP; r++){ m1 = fmaxf(m1, l1[r]); m2 = fmaxf(m2, l2[r]); }
    float s1 = 0.f, s2 = 0.f;
    #pragma unroll
    for (int r = 0; r < RP; r++){
        l1[r] = expf(l1[r]-m1); s1 += l1[r];
        l2[r] = expf(l2[r]-m2); s2 += l2[r];
    }
    float i1 = 1.f/s1, i2 = 1.f/s2;
    float4* o1 = (float4*)(lat1 + (size_t)t*RP);
    float4* o2 = (float4*)(lat2 + (size_t)t*RP);
    #pragma unroll
    for (int q = 0; q < 4; q++){
        o1[q] = make_float4(l1[4*q]*i1, l1[4*q+1]*i1, l1[4*q+2]*i1, l1[4*q+3]*i1);
        o2[q] = make_float4(l2[4*q]*i2, l2[4*q+1]*i2, l2[4*q+2]*i2, l2[4*q+3]*i2);
    }
}

// ============ per-node lat sums: C[o][r] = sum lat1, Rm[s][r] = sum lat2 ============
__global__ __launch_bounds__(256) void k_CR(const int* __restrict__ offs,
                                            const int* __restrict__ eb,
                                            const float* __restrict__ lat1,
                                            const float* __restrict__ lat2,
                                            float* __restrict__ C,
                                            float* __restrict__ Rm){
    int gid = blockIdx.x*256 + threadIdx.x;
    int n = gid >> 4, e = gid & 15;
    if (n >= NN) return;
    int b = offs[NN+n], en = offs[NN+n+1];      // by-o adjacency
    float acc = 0.f;
    for (int i = b; i < en; i++) acc += lat1[(size_t)eb[i]*16 + e];
    C[(size_t)n*16 + e] = acc;
    b = offs[n]; en = offs[n+1];                // by-s adjacency
    acc = 0.f;
    for (int i = b; i < en; i++) acc += lat2[(size_t)eb[i]*16 + e];
    Rm[(size_t)n*16 + e] = acc;
}

// ============ scalar reductions: S0[0]=sum_o C[o][0], S0[1]=sum_s Rm[s][0] ============
__global__ __launch_bounds__(256) void k_red0(const float* __restrict__ C,
                                              const float* __restrict__ Rm,
                                              float* __restrict__ S0){
    int n = blockIdx.x*256 + threadIdx.x;
    float a = (n < NN) ? C[(size_t)n*16] : 0.f;
    float b = (n < NN) ? Rm[(size_t)n*16] : 0.f;
    #pragma unroll
    for (int off = 32; off > 0; off >>= 1){
        a += __shfl_down(a, off);
        b += __shfl_down(b, off);
    }
    __shared__ float sa[4], sb[4];
    int w = threadIdx.x >> 6, l = threadIdx.x & 63;
    if (l == 0){ sa[w] = a; sb[w] = b; }
    __syncthreads();
    if (threadIdx.x == 0){
        unsafeAtomicAdd(&S0[0], sa[0]+sa[1]+sa[2]+sa[3]);
        unsafeAtomicAdd(&S0[1], sb[0]+sb[1]+sb[2]+sb[3]);
    }
}

// ============ divisor sweep: inv colsum/rowsum over flat index c ============
__global__ __launch_bounds__(256) void k_sums(const float* __restrict__ C,
                                              const float* __restrict__ Rm,
                                              const float* __restrict__ S0,
                                              float* __restrict__ invc,
                                              float* __restrict__ invr){
    int c = blockIdx.x*256 + threadIdx.x;
    if (c >= NRP) return;
    float a = 0.f, b = 0.f;
    if (c == 0){ a = S0[0]; b = S0[1]; }
    #pragma unroll
    for (int r = 1; r < RP; r++){
        int q = c / r;                      // r is a constant after unroll -> magic mul
        if (q*r == c && q < NN){
            a += C[(size_t)q*16 + r];
            b += Rm[(size_t)q*16 + r];
        }
    }
    invc[c] = (a > 0.f) ? 1.f/a : 0.f;
    invr[c] = (b > 0.f) ? 1.f/b : 0.f;
}

// ============ layer 1: h[s] = relu(bias1 + sum_t sum_r lat1[t,r]*invc[o*r]*w1[o*r]) ============
__global__ __launch_bounds__(256) void k_layer1(const int* __restrict__ offs,
                                                const int* __restrict__ eb,
                                                const int* __restrict__ ocol,
                                                const float* __restrict__ lat1,
                                                const float* __restrict__ invc,
                                                const float* __restrict__ w1,
                                                const float* __restrict__ b1,
                                                float* __restrict__ h){
    int gid = blockIdx.x*256 + threadIdx.x;
    int n = gid >> 4, e = gid & 15;
    if (n >= NN) return;
    int b = offs[n], en = offs[n+1];
    float acc = 0.f;
    for (int i = b; i < en; i++){
        int t = eb[i];
        int o = ocol[t];
        const float* lrow = lat1 + (size_t)t*16;
        #pragma unroll
        for (int r = 0; r < RP; r++){
            size_t c = (size_t)o * r;
            acc += lrow[r] * invc[c] * w1[c*16 + e];
        }
    }
    h[(size_t)n*16 + e] = fmaxf(acc + b1[e], 0.f);
}

// ============ P[s][r][e] = sum_{t in adj_s(s)} lat2[t,r] * h[o_t][e] ============
__global__ __launch_bounds__(256) void k_P(const int* __restrict__ offs,
                                           const int* __restrict__ eb,
                                           const int* __restrict__ ocol,
                                           const float* __restrict__ lat2,
                                           const float* __restrict__ h,
                                           float* __restrict__ P){
    int gid = blockIdx.x*256 + threadIdx.x;
    int n = gid >> 4, e = gid & 15;
    if (n >= NN) return;
    int b = offs[n], en = offs[n+1];
    float acc[RP];
    #pragma unroll
    for (int r = 0; r < RP; r++) acc[r] = 0.f;
    for (int i = b; i < en; i++){
        int t = eb[i];
        float hv = h[(size_t)ocol[t]*16 + e];
        const float* lrow = lat2 + (size_t)t*16;
        #pragma unroll
        for (int r = 0; r < RP; r++) acc[r] += lrow[r] * hv;
    }
    float* Pn = P + (size_t)n*256 + e;
    #pragma unroll
    for (int r = 0; r < RP; r++) Pn[r*16] = acc[r];
}

// ============ V0h[e] = sum_s P[s][0][e]  (the r=0 row of h2) ============
__global__ __launch_bounds__(256) void k_V0h(const float* __restrict__ P,
                                             float* __restrict__ S0V){
    int gid = blockIdx.x*256 + threadIdx.x;
    int n = gid >> 4, e = gid & 15;
    float v = (n < NN) ? P[(size_t)n*256 + e] : 0.f;
    __shared__ float sm[256];
    sm[threadIdx.x] = v; __syncthreads();
    if (threadIdx.x < 16){
        float s = 0.f;
        #pragma unroll
        for (int k = 0; k < 16; k++) s += sm[k*16 + threadIdx.x];
        unsafeAtomicAdd(&S0V[2 + threadIdx.x], s);
    }
}

// ============ fused h2 + output einsum ============
__global__ __launch_bounds__(256) void k_out(const float* __restrict__ P,
                                             const float* __restrict__ invr,
                                             const float* __restrict__ S0V,
                                             const float* __restrict__ w2,
                                             const float* __restrict__ b2,
                                             float* __restrict__ out){
    int n = blockIdx.x*256 + threadIdx.x;
    if (n >= NN) return;
    float acc[NUMCLS];
    #pragma unroll
    for (int cl = 0; cl < NUMCLS; cl++) acc[cl] = b2[cl];
    #pragma unroll 1
    for (int rr = 0; rr < RP; rr++){
        int c = rr*NN + n;                 // flat h2 row consumed exactly once
        float hrow[EMB];
        #pragma unroll
        for (int e = 0; e < EMB; e++) hrow[e] = 0.f;
        if (c == 0){
            #pragma unroll
            for (int e = 0; e < EMB; e++) hrow[e] = S0V[2 + e];
        }
        #pragma unroll
        for (int r = 1; r < RP; r++){
            int q = c / r;                 // const divisor -> magic mul
            if (q*r == c && q < NN){
                const float* Pr = P + (size_t)q*256 + r*16;
                #pragma unroll
                for (int e = 0; e < EMB; e++) hrow[e] += Pr[e];
            }
        }
        float inv = invr[c];
        const float* wr = w2 + (size_t)rr*EMB*NUMCLS;   // wave-uniform -> s_load
        #pragma unroll
        for (int e = 0; e < EMB; e++){
            float x = hrow[e] * inv;
            #pragma unroll
            for (int cl = 0; cl < NUMCLS; cl++) acc[cl] += x * wr[e*NUMCLS + cl];
        }
    }
    float4* op = (float4*)(out + (size_t)n*NUMCLS);
    #pragma unroll
    for (int q = 0; q < NUMCLS/4; q++)
        op[q] = make_float4(acc[4*q], acc[4*q+1], acc[4*q+2], acc[4*q+3]);
}

extern "C" void kernel_launch(void* const* d_in, const int* in_sizes, int n_in,
                              void* d_out, int out_size, void* d_ws, size_t ws_size,
                              hipStream_t stream)
{
    const float* nhots = (const float*)d_in[0];
    const float* Wl1   = (const float*)d_in[1];
    const float* bl1   = (const float*)d_in[2];
    const float* Wl2   = (const float*)d_in[3];
    const float* bl2   = (const float*)d_in[4];
    const float* w1    = (const float*)d_in[5];
    const float* w2    = (const float*)d_in[6];
    const float* b1    = (const float*)d_in[7];
    const float* b2    = (const float*)d_in[8];
    const int* srow = (const int*)d_in[9];    // hrow[t] = s[t] for t < NT
    const int* ocol = (const int*)d_in[12];   // vcol[t] = o[t] for t < NT

    // ---- workspace layout (floats), with P aliased over dead lat1/C/Rm ----
    float* base = (float*)d_ws;
    float* P    = base;                         // 25.6M floats (NN*256), live after k_layer1
    float* lat1 = base;                         // 8M, dead after k_layer1
    float* C    = base + (size_t)8000000;       // 1.6M, dead after k_sums
    float* Rm   = base + (size_t)9600000;       // 1.6M, dead after k_sums
    float* lat2 = base + (size_t)25600000;      // 8M
    float* invc = base + (size_t)33600000;      // 1.6M
    float* invr = base + (size_t)35200000;      // 1.6M
    float* h    = base + (size_t)36800000;      // 1.6M
    float* S0V  = base + (size_t)38400000;      // 32: [S0c, S0r, V0h[16], pad]
    int*   cnt  = (int*)(base + (size_t)38400032);
    int*   offs = cnt + MM;                     // MM+1
    int*   cur  = offs + (MM+1);
    int*   bsum = cur + MM;                     // SCAN_BLOCKS (pad to 1024)
    int*   btot = bsum + 1024;
    int*   eb   = btot + 1024;                  // 2*NT = 1M
    // total ~ 160 MB

    hipMemsetAsync(cnt, 0, (size_t)MM*4, stream);
    hipMemsetAsync(S0V, 0, 32*4, stream);

    const int EB = (NT + 255)/256;       // 1954
    const int NB16 = (NN*16 + 255)/256;  // 6250
    const int CB = (NRP + 255)/256;      // 6250
    const int NB = (NN + 255)/256;       // 391

    k_count   <<<EB, 256, 0, stream>>>(srow, ocol, cnt);
    k_scan_blk<<<SCAN_BLOCKS, 256, 0, stream>>>(cnt, offs, bsum);
    k_scan_top<<<1, 1024, 0, stream>>>(bsum, btot);
    k_scan_add<<<SCAN_BLOCKS, 256, 0, stream>>>(offs, btot, cur);
    k_fill    <<<EB, 256, 0, stream>>>(srow, ocol, cur, eb);
    k_lat     <<<EB, 256, 0, stream>>>(nhots, Wl1, bl1, Wl2, bl2, lat1, lat2);
    k_CR      <<<NB16, 256, 0, stream>>>(offs, eb, lat1, lat2, C, Rm);
    k_red0    <<<NB, 256, 0, stream>>>(C, Rm, S0V);
    k_sums    <<<CB, 256, 0, stream>>>(C, Rm, S0V, invc, invr);
    k_layer1  <<<NB16, 256, 0, stream>>>(offs, eb, ocol, lat1, invc, w1, b1, h);
    k_P       <<<NB16, 256, 0, stream>>>(offs, eb, ocol, lat2, h, P);
    k_V0h     <<<NB16, 256, 0, stream>>>(P, S0V);
    k_out     <<<NB, 256, 0, stream>>>(P, invr, S0V, w2, b2, (float*)d_out);
}

// Round 4
// 871.867 us; speedup vs baseline: 3.1426x; 1.0459x over previous
//
#include <hip/hip_runtime.h>
#include <stdint.h>

#define NN 100000
#define NT 500000
#define RP 16
#define RR 16
#define EMB 16
#define NUMCLS 40
#define NRP (NN*RP)          // 1,600,000
#define MM (2*NN)            // concatenated histogram length (by-s | by-o)
#define SCAN_BLOCKS ((MM + 255)/256)   // 782

// ============ CSR build ============
__global__ __launch_bounds__(256) void k_count(const int* __restrict__ s,
                                               const int* __restrict__ o,
                                               int* __restrict__ cnt){
    int t = blockIdx.x*256 + threadIdx.x;
    if (t >= NT) return;
    atomicAdd(&cnt[s[t]], 1);
    atomicAdd(&cnt[NN + o[t]], 1);
}

__global__ __launch_bounds__(256) void k_scan_blk(const int* __restrict__ cnt,
                                                  int* __restrict__ offs,
                                                  int* __restrict__ bsum){
    __shared__ int sm[256];
    int tid = threadIdx.x;
    int i = blockIdx.x*256 + tid;
    int v = (i < MM) ? cnt[i] : 0;
    sm[tid] = v; __syncthreads();
    for (int off = 1; off < 256; off <<= 1){
        int x = (tid >= off) ? sm[tid-off] : 0;
        __syncthreads();
        sm[tid] += x; __syncthreads();
    }
    if (i < MM) offs[i] = sm[tid] - v;       // exclusive within block
    if (tid == 255) bsum[blockIdx.x] = sm[255];
}

__global__ __launch_bounds__(1024) void k_scan_top(const int* __restrict__ bsum,
                                                   int* __restrict__ btot){
    __shared__ int sm[1024];
    int tid = threadIdx.x;
    int v = (tid < SCAN_BLOCKS) ? bsum[tid] : 0;
    sm[tid] = v; __syncthreads();
    for (int off = 1; off < 1024; off <<= 1){
        int x = (tid >= off) ? sm[tid-off] : 0;
        __syncthreads();
        sm[tid] += x; __syncthreads();
    }
    if (tid < SCAN_BLOCKS) btot[tid] = sm[tid] - v;   // exclusive
}

__global__ __launch_bounds__(256) void k_scan_add(int* __restrict__ offs,
                                                  const int* __restrict__ btot,
                                                  int* __restrict__ cur){
    int i = blockIdx.x*256 + threadIdx.x;
    if (i < MM){
        int v = offs[i] + btot[blockIdx.x];
        offs[i] = v;
        cur[i] = v;
    }
    if (i == 0) offs[MM] = 2*NT;
}

__global__ __launch_bounds__(256) void k_fill(const int* __restrict__ s,
                                              const int* __restrict__ o,
                                              int* __restrict__ cur,
                                              int* __restrict__ eb){
    int t = blockIdx.x*256 + threadIdx.x;
    if (t >= NT) return;
    int p = atomicAdd(&cur[s[t]], 1);      eb[p] = t;   // by-s list in [0, NT)
    int q = atomicAdd(&cur[NN + o[t]], 1); eb[q] = t;   // by-o list in [NT, 2NT)
}

// ============ lat1/lat2 softmax (pure streaming, no atomics) ============
__global__ __launch_bounds__(256) void k_lat(
    const float* __restrict__ nhots,
    const float* __restrict__ Wl1, const float* __restrict__ bl1,
    const float* __restrict__ Wl2, const float* __restrict__ bl2,
    float* __restrict__ lat1, float* __restrict__ lat2)
{
    __shared__ float sW1[RP*RR], sW2[RP*RR], sb1[RP], sb2[RP];
    int tid = threadIdx.x;
    if (tid < RP*RR){ sW1[tid] = Wl1[tid]; sW2[tid] = Wl2[tid]; }
    if (tid < RP){ sb1[tid] = bl1[tid]; sb2[tid] = bl2[tid]; }
    __syncthreads();

    int t = blockIdx.x*256 + tid;
    if (t >= NT) return;
    float nh[RR];
    const float4* npx = (const float4*)(nhots + (size_t)t * RR);
    #pragma unroll
    for (int q = 0; q < 4; q++){
        float4 v = npx[q];
        nh[4*q] = v.x; nh[4*q+1] = v.y; nh[4*q+2] = v.z; nh[4*q+3] = v.w;
    }
    float l1[RP], l2[RP];
    #pragma unroll
    for (int r = 0; r < RP; r++){
        float a = sb1[r], b = sb2[r];
        #pragma unroll
        for (int i = 0; i < RR; i++){ a += nh[i]*sW1[r*RR+i]; b += nh[i]*sW2[r*RR+i]; }
        l1[r] = a; l2[r] = b;
    }
    float m1 = l1[0], m2 = l2[0];
    #pragma unroll
    for (int r = 1; r < RP; r++){ m1 = fmaxf(m1, l1[r]); m2 = fmaxf(m2, l2[r]); }
    float s1 = 0.f, s2 = 0.f;
    #pragma unroll
    for (int r = 0; r < RP; r++){
        l1[r] = expf(l1[r]-m1); s1 += l1[r];
        l2[r] = expf(l2[r]-m2); s2 += l2[r];
    }
    float i1 = 1.f/s1, i2 = 1.f/s2;
    float4* o1 = (float4*)(lat1 + (size_t)t*RP);
    float4* o2 = (float4*)(lat2 + (size_t)t*RP);
    #pragma unroll
    for (int q = 0; q < 4; q++){
        o1[q] = make_float4(l1[4*q]*i1, l1[4*q+1]*i1, l1[4*q+2]*i1, l1[4*q+3]*i1);
        o2[q] = make_float4(l2[4*q]*i2, l2[4*q+1]*i2, l2[4*q+2]*i2, l2[4*q+3]*i2);
    }
}

// ============ per-node lat sums + fused r=0 global reductions ============
// C[o][r] = sum_{t:o_t=o} lat1[t,r];  Rm[s][r] = sum_{t:s_t=s} lat2[t,r]
// S0V[0] += sum_o C[o][0];  S0V[1] += sum_s Rm[s][0]
__global__ __launch_bounds__(256) void k_CR(const int* __restrict__ offs,
                                            const int* __restrict__ eb,
                                            const float* __restrict__ lat1,
                                            const float* __restrict__ lat2,
                                            float* __restrict__ C,
                                            float* __restrict__ Rm,
                                            float* __restrict__ S0V){
    int gid = blockIdx.x*256 + threadIdx.x;
    int n = gid >> 4, e = gid & 15;
    float accC = 0.f, accR = 0.f;
    if (n < NN){
        int b = offs[NN+n], en = offs[NN+n+1];      // by-o adjacency
        for (int i = b; i < en; i++) accC += lat1[(size_t)eb[i]*16 + e];
        C[(size_t)n*16 + e] = accC;
        b = offs[n]; en = offs[n+1];                // by-s adjacency
        for (int i = b; i < en; i++) accR += lat2[(size_t)eb[i]*16 + e];
        Rm[(size_t)n*16 + e] = accR;
    }
    __shared__ float sa[16], sb[16];
    int g = threadIdx.x >> 4;
    if (e == 0){ sa[g] = accC; sb[g] = accR; }
    __syncthreads();
    if (threadIdx.x == 0){
        float a = 0.f, b = 0.f;
        #pragma unroll
        for (int k = 0; k < 16; k++){ a += sa[k]; b += sb[k]; }
        unsafeAtomicAdd(&S0V[0], a);
        unsafeAtomicAdd(&S0V[1], b);
    }
}

// ============ divisor sweep: inv colsum/rowsum over flat index c ============
__global__ __launch_bounds__(256) void k_sums(const float* __restrict__ C,
                                              const float* __restrict__ Rm,
                                              const float* __restrict__ S0,
                                              float* __restrict__ invc,
                                              float* __restrict__ invr){
    int c = blockIdx.x*256 + threadIdx.x;
    if (c >= NRP) return;
    float a = 0.f, b = 0.f;
    if (c == 0){ a = S0[0]; b = S0[1]; }
    #pragma unroll
    for (int r = 1; r < RP; r++){
        int q = c / r;                      // const divisor -> magic mul
        if (q*r == c && q < NN){
            a += C[(size_t)q*16 + r];
            b += Rm[(size_t)q*16 + r];
        }
    }
    invc[c] = (a > 0.f) ? 1.f/a : 0.f;
    invr[c] = (b > 0.f) ? 1.f/b : 0.f;
}

// ============ layer-1 phase A (by-o): yt[t][e] = sum_r lat1[t,r]*invc[o*r]*w1[o*r][e] ============
__global__ __launch_bounds__(256) void k_y(const int* __restrict__ offs,
                                           const int* __restrict__ eb,
                                           const float* __restrict__ lat1,
                                           const float* __restrict__ invc,
                                           const float* __restrict__ w1,
                                           float* __restrict__ yt){
    int gid = blockIdx.x*256 + threadIdx.x;
    int o = gid >> 4, e = gid & 15;
    if (o >= NN) return;
    float Wb[RP];                         // thread e holds column e of the 16x16 block
    #pragma unroll
    for (int r = 0; r < RP; r++){
        size_t c = (size_t)o * r;
        Wb[r] = invc[c] * w1[c*16 + e];   // each w1 row read ONCE per node (not per edge)
    }
    int b = offs[NN+o], en = offs[NN+o+1];
    for (int i = b; i < en; i++){
        int t = eb[i];
        const float4* lp = (const float4*)(lat1 + (size_t)t*16);
        float y = 0.f;
        #pragma unroll
        for (int q = 0; q < 4; q++){
            float4 v = lp[q];
            y += v.x*Wb[4*q] + v.y*Wb[4*q+1] + v.z*Wb[4*q+2] + v.w*Wb[4*q+3];
        }
        yt[(size_t)t*16 + e] = y;
    }
}

// ============ layer-1 phase B (by-s): h[s] = relu(b1 + sum_t yt[t]) ============
__global__ __launch_bounds__(256) void k_h(const int* __restrict__ offs,
                                           const int* __restrict__ eb,
                                           const float* __restrict__ yt,
                                           const float* __restrict__ b1,
                                           float* __restrict__ h){
    int gid = blockIdx.x*256 + threadIdx.x;
    int n = gid >> 4, e = gid & 15;
    if (n >= NN) return;
    int b = offs[n], en = offs[n+1];
    float acc = 0.f;
    for (int i = b; i < en; i++) acc += yt[(size_t)eb[i]*16 + e];
    h[(size_t)n*16 + e] = fmaxf(acc + b1[e], 0.f);
}

// ============ P[s][r][e] = sum_{t in adj_s(s)} lat2[t,r]*h[o_t][e]; fused V0h ============
__global__ __launch_bounds__(256) void k_P(const int* __restrict__ offs,
                                           const int* __restrict__ eb,
                                           const int* __restrict__ ocol,
                                           const float* __restrict__ lat2,
                                           const float* __restrict__ h,
                                           float* __restrict__ P,
                                           float* __restrict__ S0V){
    int gid = blockIdx.x*256 + threadIdx.x;
    int n = gid >> 4, e = gid & 15;
    float acc[RP];
    #pragma unroll
    for (int r = 0; r < RP; r++) acc[r] = 0.f;
    if (n < NN){
        int b = offs[n], en = offs[n+1];
        for (int i = b; i < en; i++){
            int t = eb[i];
            float hv = h[(size_t)ocol[t]*16 + e];
            const float* lrow = lat2 + (size_t)t*16;
            #pragma unroll
            for (int r = 0; r < RP; r++) acc[r] += lrow[r] * hv;
        }
        float* Pn = P + (size_t)n*256 + e;
        #pragma unroll
        for (int r = 0; r < RP; r++) Pn[r*16] = acc[r];
    }
    // fused: V0h[e] = sum_s P[s][0][e]
    __shared__ float sm[256];
    sm[threadIdx.x] = acc[0]; __syncthreads();
    if (threadIdx.x < 16){
        float s = 0.f;
        #pragma unroll
        for (int k = 0; k < 16; k++) s += sm[k*16 + threadIdx.x];
        unsafeAtomicAdd(&S0V[2 + threadIdx.x], s);
    }
}

// ============ fused h2 + output einsum ============
__global__ __launch_bounds__(256) void k_out(const float* __restrict__ P,
                                             const float* __restrict__ invr,
                                             const float* __restrict__ S0V,
                                             const float* __restrict__ w2,
                                             const float* __restrict__ b2,
                                             float* __restrict__ out){
    int n = blockIdx.x*256 + threadIdx.x;
    if (n >= NN) return;
    float acc[NUMCLS];
    #pragma unroll
    for (int cl = 0; cl < NUMCLS; cl++) acc[cl] = b2[cl];
    #pragma unroll 1
    for (int rr = 0; rr < RP; rr++){
        int c = rr*NN + n;                 // flat h2 row consumed exactly once
        float hrow[EMB];
        #pragma unroll
        for (int e = 0; e < EMB; e++) hrow[e] = 0.f;
        if (c == 0){
            #pragma unroll
            for (int e = 0; e < EMB; e++) hrow[e] = S0V[2 + e];
        }
        #pragma unroll
        for (int r = 1; r < RP; r++){
            int q = c / r;                 // const divisor -> magic mul
            if (q*r == c && q < NN){
                const float* Pr = P + (size_t)q*256 + r*16;
                #pragma unroll
                for (int e = 0; e < EMB; e++) hrow[e] += Pr[e];
            }
        }
        float inv = invr[c];
        const float* wr = w2 + (size_t)rr*EMB*NUMCLS;   // wave-uniform -> s_load
        #pragma unroll
        for (int e = 0; e < EMB; e++){
            float x = hrow[e] * inv;
            #pragma unroll
            for (int cl = 0; cl < NUMCLS; cl++) acc[cl] += x * wr[e*NUMCLS + cl];
        }
    }
    float4* op = (float4*)(out + (size_t)n*NUMCLS);
    #pragma unroll
    for (int q = 0; q < NUMCLS/4; q++)
        op[q] = make_float4(acc[4*q], acc[4*q+1], acc[4*q+2], acc[4*q+3]);
}

extern "C" void kernel_launch(void* const* d_in, const int* in_sizes, int n_in,
                              void* d_out, int out_size, void* d_ws, size_t ws_size,
                              hipStream_t stream)
{
    const float* nhots = (const float*)d_in[0];
    const float* Wl1   = (const float*)d_in[1];
    const float* bl1   = (const float*)d_in[2];
    const float* Wl2   = (const float*)d_in[3];
    const float* bl2   = (const float*)d_in[4];
    const float* w1    = (const float*)d_in[5];
    const float* w2    = (const float*)d_in[6];
    const float* b1    = (const float*)d_in[7];
    const float* b2    = (const float*)d_in[8];
    const int* srow = (const int*)d_in[9];    // hrow[t] = s[t] for t < NT
    const int* ocol = (const int*)d_in[12];   // vcol[t] = o[t] for t < NT

    // ---- workspace layout (floats) ----
    // Lifetimes: lat1 dead after k_y; C/Rm dead after k_sums; yt (aliased over
    // C/Rm + unused mid-P) live only k_y -> k_h; P written by k_P afterwards.
    float* base = (float*)d_ws;
    float* P    = base;                         // 25.6M floats (NN*256)
    float* lat1 = base;                         // 8M
    float* C    = base + (size_t)8000000;       // 1.6M
    float* Rm   = base + (size_t)9600000;       // 1.6M
    float* yt   = base + (size_t)8000000;       // 8M  (aliases C/Rm after k_sums)
    float* lat2 = base + (size_t)25600000;      // 8M
    float* invc = base + (size_t)33600000;      // 1.6M
    float* invr = base + (size_t)35200000;      // 1.6M
    float* h    = base + (size_t)36800000;      // 1.6M
    float* S0V  = base + (size_t)38400000;      // 32: [S0c, S0r, V0h[16], pad]
    int*   cnt  = (int*)(base + (size_t)38400032);
    int*   offs = cnt + MM;                     // MM+1
    int*   cur  = offs + (MM+1);
    int*   bsum = cur + MM;                     // SCAN_BLOCKS (pad to 1024)
    int*   btot = bsum + 1024;
    int*   eb   = btot + 1024;                  // 2*NT = 1M
    // total ~160 MB

    hipMemsetAsync(cnt, 0, (size_t)MM*4, stream);
    hipMemsetAsync(S0V, 0, 32*4, stream);

    const int EB = (NT + 255)/256;       // 1954
    const int NB16 = (NN*16 + 255)/256;  // 6250
    const int CB = (NRP + 255)/256;      // 6250
    const int NB = (NN + 255)/256;       // 391

    k_count   <<<EB, 256, 0, stream>>>(srow, ocol, cnt);
    k_scan_blk<<<SCAN_BLOCKS, 256, 0, stream>>>(cnt, offs, bsum);
    k_scan_top<<<1, 1024, 0, stream>>>(bsum, btot);
    k_scan_add<<<SCAN_BLOCKS, 256, 0, stream>>>(offs, btot, cur);
    k_fill    <<<EB, 256, 0, stream>>>(srow, ocol, cur, eb);
    k_lat     <<<EB, 256, 0, stream>>>(nhots, Wl1, bl1, Wl2, bl2, lat1, lat2);
    k_CR      <<<NB16, 256, 0, stream>>>(offs, eb, lat1, lat2, C, Rm, S0V);
    k_sums    <<<CB, 256, 0, stream>>>(C, Rm, S0V, invc, invr);
    k_y       <<<NB16, 256, 0, stream>>>(offs, eb, lat1, invc, w1, yt);
    k_h       <<<NB16, 256, 0, stream>>>(offs, eb, yt, b1, h);
    k_P       <<<NB16, 256, 0, stream>>>(offs, eb, ocol, lat2, h, P, S0V);
    k_out     <<<NB, 256, 0, stream>>>(P, invr, S0V, w2, b2, (float*)d_out);
}